// Round 1
// baseline (4514.105 us; speedup 1.0000x reference)
//
#include <hip/hip_runtime.h>
#include <cstdint>
#include <math.h>

#define NQ 900
#define NT 128
#define NC 91

typedef unsigned long long u64;
typedef unsigned int u32;

// monotone (total-order-preserving) mapping f32 -> u32
__device__ __forceinline__ u32 fmono(float f){
  u32 u = __float_as_uint(f);
  return (u & 0x80000000u) ? ~u : (u | 0x80000000u);
}

// ---------------- kernel 0: per-(b,q) softmax max & denom ----------------
__global__ void softmax_stats_kernel(const float* __restrict__ logits,
                                     float* __restrict__ stats, int nrows){
  int gw   = (int)((blockIdx.x * blockDim.x + threadIdx.x) >> 6);
  int lane = threadIdx.x & 63;
  if (gw >= nrows) return;
  const float* row = logits + (size_t)gw * NC;
  float v0 = (lane      < NC) ? row[lane]      : -INFINITY;
  float v1 = (lane + 64 < NC) ? row[lane + 64] : -INFINITY;
  float m = fmaxf(v0, v1);
  #pragma unroll
  for (int off = 32; off; off >>= 1) m = fmaxf(m, __shfl_xor(m, off));
  float s = ((lane < NC) ? expf(v0 - m) : 0.0f)
          + ((lane + 64 < NC) ? expf(v1 - m) : 0.0f);
  #pragma unroll
  for (int off = 32; off; off >>= 1) s += __shfl_xor(s, off);
  if (lane == 0){ stats[2*gw] = m; stats[2*gw+1] = s; }
}

// ---------------- kernel 1: cost matrix C[b][q][t] ----------------
__global__ void cost_kernel(const float* __restrict__ logits,
                            const float* __restrict__ pboxes,
                            const int*   __restrict__ labels,
                            const float* __restrict__ tboxes,
                            const float* __restrict__ stats,
                            float* __restrict__ Cout, int total){
#pragma clang fp contract(off)
  int idx = blockIdx.x * blockDim.x + threadIdx.x;
  if (idx >= total) return;
  int t  = idx & (NT - 1);
  int bq = idx >> 7;            // NT == 128
  int b  = bq / NQ;

  // class cost: -softmax(logits)[q, label[t]]
  int   lab = labels[b*NT + t];
  float l   = logits[(size_t)bq*NC + lab];
  float m   = stats[2*bq], s = stats[2*bq+1];
  float cclass = -(expf(l - m) / s);

  const float* pb = pboxes + (size_t)bq*4;
  const float* tb = tboxes + ((size_t)b*NT + t)*4;
  float pcx = pb[0], pcy = pb[1], pw = pb[2], ph = pb[3];
  float tcx = tb[0], tcy = tb[1], tw = tb[2], th = tb[3];

  // L1 cdist on raw cxcywh, left-assoc sum like jnp.sum over size-4 axis
  float cbbox = ((fabsf(pcx-tcx) + fabsf(pcy-tcy)) + fabsf(pw-tw)) + fabsf(ph-th);

  // cxcywh -> xyxy (exact op order of reference)
  float px0 = pcx - 0.5f*pw, py0 = pcy - 0.5f*ph;
  float px1 = pcx + 0.5f*pw, py1 = pcy + 0.5f*ph;
  float tx0 = tcx - 0.5f*tw, ty0 = tcy - 0.5f*th;
  float tx1 = tcx + 0.5f*tw, ty1 = tcy + 0.5f*th;

  float area1 = (px1 - px0) * (py1 - py0);
  float area2 = (tx1 - tx0) * (ty1 - ty0);
  float ltx = fmaxf(px0, tx0), lty = fmaxf(py0, ty0);
  float rbx = fminf(px1, tx1), rby = fminf(py1, ty1);
  float wx = fmaxf(rbx - ltx, 0.0f), wy = fmaxf(rby - lty, 0.0f);
  float inter = wx * wy;
  float uni   = (area1 + area2) - inter;
  float iou   = inter / uni;
  float cx0 = fminf(px0, tx0), cy0 = fminf(py0, ty0);
  float cx1 = fmaxf(px1, tx1), cy1 = fmaxf(py1, ty1);
  float cwx = fmaxf(cx1 - cx0, 0.0f), cwy = fmaxf(cy1 - cy0, 0.0f);
  float areac = cwx * cwy;
  float giou  = iou - (areac - uni) / areac;

  // COST_CLASS*cc + COST_BBOX*cb - COST_GIOU*giou, Python eval order
  float cost = (cclass + 5.0f*cbbox) - 2.0f*giou;
  Cout[idx] = cost;
}

// ---------------- kernel 2: greedy matching, one block per batch ----------------
#define INACT 0xFFFFFFFFu

__global__ __launch_bounds__(256) void greedy_kernel(const float* __restrict__ Cmat,
                                                     float* __restrict__ outsrc,
                                                     float* __restrict__ outtgt,
                                                     int T_total){
  int b   = blockIdx.x;
  int tid = threadIdx.x;
  int lane = tid & 63, wid = tid >> 6;
  const float* Cb = Cmat + (size_t)b * NQ * NT;

  __shared__ u32          rowv[NQ];   // monotone-mapped row min value
  __shared__ unsigned char rowc[NQ];  // argmin col (first occurrence)
  __shared__ unsigned char used[NT];
  __shared__ u64          wred[4];
  __shared__ int          sh_j;

  for (int t = tid; t < NT; t += 256) used[t] = 0;

  // init per-row minima (first-min tie-break via strict < ascending t)
  for (int q = tid; q < NQ; q += 256){
    const float4* r = (const float4*)(Cb + (size_t)q * NT);
    float best = INFINITY; int bc = 0;
    #pragma unroll 4
    for (int t4 = 0; t4 < NT/4; ++t4){
      float4 v = r[t4];
      if (v.x < best){ best = v.x; bc = t4*4 + 0; }
      if (v.y < best){ best = v.y; bc = t4*4 + 1; }
      if (v.z < best){ best = v.z; bc = t4*4 + 2; }
      if (v.w < best){ best = v.w; bc = t4*4 + 3; }
    }
    rowv[q] = fmono(best);
    rowc[q] = (unsigned char)bc;
  }
  __syncthreads();

  for (int step = 0; step < NT; ++step){
    // global argmin over row minima; key = (monoval<<32)|row -> row-major ties
    u64 best = ~0ull;
    for (int q = tid; q < NQ; q += 256){
      u64 key = ((u64)rowv[q] << 32) | (u32)q;
      best = best < key ? best : key;
    }
    #pragma unroll
    for (int off = 32; off; off >>= 1){
      u64 o = __shfl_xor(best, off);
      best = best < o ? best : o;
    }
    if (lane == 0) wred[wid] = best;
    __syncthreads();
    if (tid == 0){
      u64 bb = wred[0];
      for (int w = 1; w < 4; ++w) bb = bb < wred[w] ? bb : wred[w];
      int i = (int)(bb & 0xFFFFFFFFu);
      int j = rowc[i];
      sh_j = j;
      outsrc[b*NT + step] = (float)i;
      outtgt[b*NT + step] = (float)j;
      rowv[i] = INACT;
      used[j] = 1;
    }
    __syncthreads();
    if (step == NT - 1) break;
    int j = sh_j;
    // rows whose cached argmin column was just removed: rescan active cols
    for (int q = tid; q < NQ; q += 256){
      if (rowv[q] != INACT && rowc[q] == (unsigned char)j){
        const float* r = Cb + (size_t)q * NT;
        float best2 = INFINITY; int bc = -1;
        for (int t = 0; t < NT; ++t){
          if (!used[t]){
            float v = r[t];
            if (v < best2){ best2 = v; bc = t; }
          }
        }
        rowv[q] = (bc >= 0) ? fmono(best2) : INACT;
        rowc[q] = (unsigned char)(bc >= 0 ? bc : 0);
      }
    }
    __syncthreads();
  }
  (void)T_total;
}

extern "C" void kernel_launch(void* const* d_in, const int* in_sizes, int n_in,
                              void* d_out, int out_size, void* d_ws, size_t ws_size,
                              hipStream_t stream){
  const float* logits = (const float*)d_in[0];
  const float* pboxes = (const float*)d_in[1];
  const int*   labels = (const int*)  d_in[2];
  const float* tboxes = (const float*)d_in[3];
  int B = in_sizes[0] / (NQ * NC);

  float* out    = (float*)d_out;
  float* outsrc = out;
  float* outtgt = out + (size_t)B * NT;
  float* Cmat   = out + (size_t)2 * B * NT;
  float* stats  = (float*)d_ws;          // B*NQ*2 floats

  int nrows = B * NQ;
  int blocks0 = (nrows + 3) / 4;         // 4 waves (rows) per 256-thread block
  softmax_stats_kernel<<<blocks0, 256, 0, stream>>>(logits, stats, nrows);

  int total = B * NQ * NT;
  cost_kernel<<<(total + 255) / 256, 256, 0, stream>>>(logits, pboxes, labels,
                                                       tboxes, stats, Cmat, total);

  greedy_kernel<<<B, 256, 0, stream>>>(Cmat, outsrc, outtgt, NT);
}

// Round 3
// 913.176 us; speedup vs baseline: 4.9433x; 4.9433x over previous
//
#include <hip/hip_runtime.h>
#include <cstdint>
#include <math.h>

#define NQ 900
#define NT 128
#define NC 91

typedef unsigned long long u64;
typedef unsigned int u32;

#define INACT_KEY 0xFFFFFFFFFFFFFFFFull

// monotone (total-order-preserving) mapping f32 -> u32
__device__ __forceinline__ u32 fmono(float f){
  u32 u = __float_as_uint(f);
  return (u & 0x80000000u) ? ~u : (u | 0x80000000u);
}

// ---------------- kernel 0: per-(b,q) softmax max & denom ----------------
__global__ void softmax_stats_kernel(const float* __restrict__ logits,
                                     float* __restrict__ stats, int nrows){
  int gw   = (int)((blockIdx.x * blockDim.x + threadIdx.x) >> 6);
  int lane = threadIdx.x & 63;
  if (gw >= nrows) return;
  const float* row = logits + (size_t)gw * NC;
  float v0 = (lane      < NC) ? row[lane]      : -INFINITY;
  float v1 = (lane + 64 < NC) ? row[lane + 64] : -INFINITY;
  float m = fmaxf(v0, v1);
  #pragma unroll
  for (int off = 32; off; off >>= 1) m = fmaxf(m, __shfl_xor(m, off));
  float s = ((lane < NC) ? expf(v0 - m) : 0.0f)
          + ((lane + 64 < NC) ? expf(v1 - m) : 0.0f);
  #pragma unroll
  for (int off = 32; off; off >>= 1) s += __shfl_xor(s, off);
  if (lane == 0){ stats[2*gw] = m; stats[2*gw+1] = s; }
}

// ---------------- kernel 1: cost matrix C[b][q][t] (UNCHANGED — bit-exact) ----------------
__global__ void cost_kernel(const float* __restrict__ logits,
                            const float* __restrict__ pboxes,
                            const int*   __restrict__ labels,
                            const float* __restrict__ tboxes,
                            const float* __restrict__ stats,
                            float* __restrict__ Cout, int total){
#pragma clang fp contract(off)
  int idx = blockIdx.x * blockDim.x + threadIdx.x;
  if (idx >= total) return;
  int t  = idx & (NT - 1);
  int bq = idx >> 7;            // NT == 128
  int b  = bq / NQ;

  int   lab = labels[b*NT + t];
  float l   = logits[(size_t)bq*NC + lab];
  float m   = stats[2*bq], s = stats[2*bq+1];
  float cclass = -(expf(l - m) / s);

  const float* pb = pboxes + (size_t)bq*4;
  const float* tb = tboxes + ((size_t)b*NT + t)*4;
  float pcx = pb[0], pcy = pb[1], pw = pb[2], ph = pb[3];
  float tcx = tb[0], tcy = tb[1], tw = tb[2], th = tb[3];

  float cbbox = ((fabsf(pcx-tcx) + fabsf(pcy-tcy)) + fabsf(pw-tw)) + fabsf(ph-th);

  float px0 = pcx - 0.5f*pw, py0 = pcy - 0.5f*ph;
  float px1 = pcx + 0.5f*pw, py1 = pcy + 0.5f*ph;
  float tx0 = tcx - 0.5f*tw, ty0 = tcy - 0.5f*th;
  float tx1 = tcx + 0.5f*tw, ty1 = tcy + 0.5f*th;

  float area1 = (px1 - px0) * (py1 - py0);
  float area2 = (tx1 - tx0) * (ty1 - ty0);
  float ltx = fmaxf(px0, tx0), lty = fmaxf(py0, ty0);
  float rbx = fminf(px1, tx1), rby = fminf(py1, ty1);
  float wx = fmaxf(rbx - ltx, 0.0f), wy = fmaxf(rby - lty, 0.0f);
  float inter = wx * wy;
  float uni   = (area1 + area2) - inter;
  float iou   = inter / uni;
  float cx0 = fminf(px0, tx0), cy0 = fminf(py0, ty0);
  float cx1 = fmaxf(px1, tx1), cy1 = fmaxf(py1, ty1);
  float cwx = fmaxf(cx1 - cx0, 0.0f), cwy = fmaxf(cy1 - cy0, 0.0f);
  float areac = cwx * cwy;
  float giou  = iou - (areac - uni) / areac;

  float cost = (cclass + 5.0f*cbbox) - 2.0f*giou;
  Cout[idx] = cost;
}

// ---------------- kernel 2: greedy matching, one block per batch ----------------
// key[q] = (fmono(rowmin) << 32) | q  -> u64 min == (value, row) lexicographic
// Rescan of invalidated rows is WAVE-parallel: one coalesced float2 row read
// + 6-level u64 shuffle reduce with (value, col) key (first-occurrence ties).
__global__ __launch_bounds__(256) void greedy_kernel(const float* __restrict__ Cmat,
                                                     float* __restrict__ outsrc,
                                                     float* __restrict__ outtgt){
  int b   = blockIdx.x;
  int tid = threadIdx.x;
  int lane = tid & 63, wid = tid >> 6;
  const float* Cb = Cmat + (size_t)b * NQ * NT;

  __shared__ u64            key[NQ];    // (mono<<32)|q, INACT_KEY when removed
  __shared__ unsigned char  rowc[NQ];   // cached argmin col (first occurrence)
  __shared__ unsigned char  used[NT];
  __shared__ u64            wred[4];
  __shared__ unsigned short wl[NQ];     // rescan worklist
  __shared__ int            wcnt;

  for (int t = tid; t < NT; t += 256) used[t] = 0;

  // init per-row minima
  for (int q = tid; q < NQ; q += 256){
    const float4* r = (const float4*)(Cb + (size_t)q * NT);
    float best = INFINITY; int bc = 0;
    #pragma unroll 4
    for (int t4 = 0; t4 < NT/4; ++t4){
      float4 v = r[t4];
      if (v.x < best){ best = v.x; bc = t4*4 + 0; }
      if (v.y < best){ best = v.y; bc = t4*4 + 1; }
      if (v.z < best){ best = v.z; bc = t4*4 + 2; }
      if (v.w < best){ best = v.w; bc = t4*4 + 3; }
    }
    key[q]  = ((u64)fmono(best) << 32) | (u32)q;
    rowc[q] = (unsigned char)bc;
  }
  __syncthreads();

  for (int step = 0; step < NT; ++step){
    // ---- Phase A: global argmin over row-min keys ----
    u64 best = INACT_KEY;
    #pragma unroll
    for (int k = 0; k < 4; ++k){
      int q = tid + k*256;
      if (q < NQ){ u64 kk = key[q]; best = kk < best ? kk : best; }
    }
    #pragma unroll
    for (int off = 32; off; off >>= 1){
      u64 o = __shfl_xor(best, off);
      best = o < best ? o : best;
    }
    if (lane == 0) wred[wid] = best;
    __syncthreads();                       // bar1: wred complete
    u64 bb = wred[0];
    bb = wred[1] < bb ? wred[1] : bb;
    bb = wred[2] < bb ? wred[2] : bb;
    bb = wred[3] < bb ? wred[3] : bb;
    int i = (int)(bb & 0xFFFFFFFFu);
    int j = rowc[i];
    if (tid == 0){
      outsrc[b*NT + step] = (float)i;
      outtgt[b*NT + step] = (float)j;
      key[i]  = INACT_KEY;
      used[j] = 1;
      wcnt    = 0;
    }
    __syncthreads();                       // bar2: removal + wcnt reset visible
    if (step == NT - 1) break;

    // ---- Phase B: build worklist of rows whose cached argmin col died ----
    #pragma unroll
    for (int k = 0; k < 4; ++k){
      int q = tid + k*256;
      if (q < NQ && key[q] != INACT_KEY && rowc[q] == (unsigned char)j){
        int p = atomicAdd(&wcnt, 1);
        wl[p] = (unsigned short)q;
      }
    }
    __syncthreads();                       // bar3: worklist complete

    // ---- Phase C: wave-parallel rescan (one wave per row) ----
    int cnt = wcnt;
    for (int w = wid; w < cnt; w += 4){
      int q = wl[w];
      const float2* r = (const float2*)(Cb + (size_t)q * NT);
      float2 v = r[lane];
      int t0 = 2*lane, t1 = t0 + 1;
      u64 k0 = used[t0] ? INACT_KEY : (((u64)fmono(v.x) << 32) | (u32)t0);
      u64 k1 = used[t1] ? INACT_KEY : (((u64)fmono(v.y) << 32) | (u32)t1);
      u64 kb = k1 < k0 ? k1 : k0;
      #pragma unroll
      for (int off = 32; off; off >>= 1){
        u64 o = __shfl_xor(kb, off);
        kb = o < kb ? o : kb;
      }
      if (lane == 0){
        int bc = (int)(kb & 0xFFFFFFFFu);
        key[q]  = (kb & 0xFFFFFFFF00000000ull) | (u32)q;
        rowc[q] = (unsigned char)bc;
      }
    }
    __syncthreads();                       // bar4: key updates visible for next A
  }
}

extern "C" void kernel_launch(void* const* d_in, const int* in_sizes, int n_in,
                              void* d_out, int out_size, void* d_ws, size_t ws_size,
                              hipStream_t stream){
  const float* logits = (const float*)d_in[0];
  const float* pboxes = (const float*)d_in[1];
  const int*   labels = (const int*)  d_in[2];
  const float* tboxes = (const float*)d_in[3];
  int B = in_sizes[0] / (NQ * NC);

  float* out    = (float*)d_out;
  float* outsrc = out;
  float* outtgt = out + (size_t)B * NT;
  float* Cmat   = out + (size_t)2 * B * NT;
  float* stats  = (float*)d_ws;          // B*NQ*2 floats

  int nrows = B * NQ;
  int blocks0 = (nrows + 3) / 4;
  softmax_stats_kernel<<<blocks0, 256, 0, stream>>>(logits, stats, nrows);

  int total = B * NQ * NT;
  cost_kernel<<<(total + 255) / 256, 256, 0, stream>>>(logits, pboxes, labels,
                                                       tboxes, stats, Cmat, total);

  greedy_kernel<<<B, 256, 0, stream>>>(Cmat, outsrc, outtgt);
}

// Round 4
// 346.714 us; speedup vs baseline: 13.0197x; 2.6338x over previous
//
#include <hip/hip_runtime.h>
#include <cstdint>
#include <math.h>

#define NQ 900
#define NT 128
#define NC 91
#define KROWS 15   // ceil(900/64)

typedef unsigned long long u64;
typedef unsigned int u32;

// ---------------- kernel 0: per-(b,q) softmax max & denom (UNCHANGED) ----------------
__global__ void softmax_stats_kernel(const float* __restrict__ logits,
                                     float* __restrict__ stats, int nrows){
  int gw   = (int)((blockIdx.x * blockDim.x + threadIdx.x) >> 6);
  int lane = threadIdx.x & 63;
  if (gw >= nrows) return;
  const float* row = logits + (size_t)gw * NC;
  float v0 = (lane      < NC) ? row[lane]      : -INFINITY;
  float v1 = (lane + 64 < NC) ? row[lane + 64] : -INFINITY;
  float m = fmaxf(v0, v1);
  #pragma unroll
  for (int off = 32; off; off >>= 1) m = fmaxf(m, __shfl_xor(m, off));
  float s = ((lane < NC) ? expf(v0 - m) : 0.0f)
          + ((lane + 64 < NC) ? expf(v1 - m) : 0.0f);
  #pragma unroll
  for (int off = 32; off; off >>= 1) s += __shfl_xor(s, off);
  if (lane == 0){ stats[2*gw] = m; stats[2*gw+1] = s; }
}

// ---------------- kernel 1: cost matrix C[b][q][t] (UNCHANGED — bit-exact) ----------------
__global__ void cost_kernel(const float* __restrict__ logits,
                            const float* __restrict__ pboxes,
                            const int*   __restrict__ labels,
                            const float* __restrict__ tboxes,
                            const float* __restrict__ stats,
                            float* __restrict__ Cout, int total){
#pragma clang fp contract(off)
  int idx = blockIdx.x * blockDim.x + threadIdx.x;
  if (idx >= total) return;
  int t  = idx & (NT - 1);
  int bq = idx >> 7;            // NT == 128
  int b  = bq / NQ;

  int   lab = labels[b*NT + t];
  float l   = logits[(size_t)bq*NC + lab];
  float m   = stats[2*bq], s = stats[2*bq+1];
  float cclass = -(expf(l - m) / s);

  const float* pb = pboxes + (size_t)bq*4;
  const float* tb = tboxes + ((size_t)b*NT + t)*4;
  float pcx = pb[0], pcy = pb[1], pw = pb[2], ph = pb[3];
  float tcx = tb[0], tcy = tb[1], tw = tb[2], th = tb[3];

  float cbbox = ((fabsf(pcx-tcx) + fabsf(pcy-tcy)) + fabsf(pw-tw)) + fabsf(ph-th);

  float px0 = pcx - 0.5f*pw, py0 = pcy - 0.5f*ph;
  float px1 = pcx + 0.5f*pw, py1 = pcy + 0.5f*ph;
  float tx0 = tcx - 0.5f*tw, ty0 = tcy - 0.5f*th;
  float tx1 = tcx + 0.5f*tw, ty1 = tcy + 0.5f*th;

  float area1 = (px1 - px0) * (py1 - py0);
  float area2 = (tx1 - tx0) * (ty1 - ty0);
  float ltx = fmaxf(px0, tx0), lty = fmaxf(py0, ty0);
  float rbx = fminf(px1, tx1), rby = fminf(py1, ty1);
  float wx = fmaxf(rbx - ltx, 0.0f), wy = fmaxf(rby - lty, 0.0f);
  float inter = wx * wy;
  float uni   = (area1 + area2) - inter;
  float iou   = inter / uni;
  float cx0 = fminf(px0, tx0), cy0 = fminf(py0, ty0);
  float cx1 = fmaxf(px1, tx1), cy1 = fmaxf(py1, ty1);
  float cwx = fmaxf(cx1 - cx0, 0.0f), cwy = fmaxf(cy1 - cy0, 0.0f);
  float areac = cwx * cwy;
  float giou  = iou - (areac - uni) / areac;

  float cost = (cclass + 5.0f*cbbox) - 2.0f*giou;
  Cout[idx] = cost;
}

// ---------------- kernel 2: greedy matching — 1 wave/batch, no LDS, no barriers ----------------
// Per lane: 2 columns, each with exact top-2 (value,row) over active rows.
// row field bit 10 = STALE (slot1: value is a lower bound, argrow unknown)
//                  = DEAD  (slot2: that element's row died; value kept as bound)
// Global pop: (val, row, col) lexicographic == reference flat argmin order.
// Stale columns compete with their bound; rescanned lazily only when popped.
__global__ __launch_bounds__(64) void greedy_kernel(const float* __restrict__ Cmat,
                                                    float* __restrict__ outsrc,
                                                    float* __restrict__ outtgt){
  const int b    = blockIdx.x;
  const int lane = threadIdx.x;          // 0..63
  const float* Cb = Cmat + (size_t)b * NQ * NT;
  const u32 colA = 2*lane, colB = 2*lane + 1;

  // ---- init: exact top-2 per column (ascending r scan; strict < = first occurrence)
  float a1 = INFINITY, a2 = INFINITY; u32 ar1 = 0, ar2 = 0;
  float b1 = INFINITY, b2 = INFINITY; u32 br1 = 0, br2 = 0;
  #pragma unroll 4
  for (int r = 0; r < NQ; ++r){
    float2 v = *(const float2*)(Cb + (size_t)r * NT + colA);
    bool l1 = v.x < a1, l2 = v.x < a2;
    a2  = l1 ? a1  : (l2 ? v.x    : a2);
    ar2 = l1 ? ar1 : (l2 ? (u32)r : ar2);
    a1  = l1 ? v.x    : a1;
    ar1 = l1 ? (u32)r : ar1;
    bool m1 = v.y < b1, m2 = v.y < b2;
    b2  = m1 ? b1  : (m2 ? v.y    : b2);
    br2 = m1 ? br1 : (m2 ? (u32)r : br2);
    b1  = m1 ? v.y    : b1;
    br1 = m1 ? (u32)r : br1;
  }

  // row-dead bitmask, wave-uniform (scalarized via readfirstlane-derived i)
  u64 rd[KROWS];
  #pragma unroll
  for (int k = 0; k < KROWS; ++k) rd[k] = 0;

  for (int step = 0; step < NT; ++step){
    u32 gm;
    while (true){
      // local candidate: lexicographic (value, meta) over this lane's 2 cols
      u32 metaA = (ar1 << 7) | colA;     // bit17 = stale
      u32 metaB = (br1 << 7) | colB;
      bool bs = (b1 < a1) || ((b1 == a1) && (metaB < metaA));
      float lv = bs ? b1 : a1;
      u32   lm = bs ? metaB : metaA;
      // phase 1: wave-min value (butterfly -> all lanes)
      float gv = lv;
      #pragma unroll
      for (int off = 1; off < 64; off <<= 1) gv = fminf(gv, __shfl_xor(gv, off));
      // phase 2: min meta among value-ties
      u32 mm = (lv == gv) ? lm : 0xFFFFFFFFu;
      #pragma unroll
      for (int off = 1; off < 64; off <<= 1){
        u32 o = (u32)__shfl_xor((int)mm, off);
        mm = o < mm ? o : mm;
      }
      u32 gms = (u32)__builtin_amdgcn_readfirstlane((int)mm);

      if (gms & (1u << 17)){
        // ---- lazy rescan of stale column jj over active rows (cooperative) ----
        int jj = (int)(gms & 0x7Fu);
        float w1 = INFINITY, w2 = INFINITY; u32 s1 = 0, s2 = 0;
        #pragma unroll
        for (int k = 0; k < KROWS; ++k){
          int r = lane + 64*k;
          float v = INFINITY;
          if (r < NQ){
            bool dead = ((rd[k] >> lane) & 1ull) != 0ull;
            float cv = Cb[(size_t)r * NT + jj];
            v = dead ? INFINITY : cv;
          }
          bool l1r = v < w1, l2r = v < w2;
          w2 = l1r ? w1 : (l2r ? v : w2);
          s2 = l1r ? s1 : (l2r ? (u32)(lane + 64*k) : s2);
          w1 = l1r ? v : w1;
          s1 = l1r ? (u32)(lane + 64*k) : s1;
        }
        // global top-2 across lanes
        float g1 = w1;
        #pragma unroll
        for (int off = 1; off < 64; off <<= 1) g1 = fminf(g1, __shfl_xor(g1, off));
        u32 t1 = (w1 == g1) ? s1 : 0xFFFFFFFFu;
        #pragma unroll
        for (int off = 1; off < 64; off <<= 1){
          u32 o = (u32)__shfl_xor((int)t1, off); t1 = o < t1 ? o : t1;
        }
        u32 r1w = (u32)__builtin_amdgcn_readfirstlane((int)t1);
        bool own = (w1 == g1) && (s1 == r1w);
        float cw = own ? w2 : w1;
        u32   cr = own ? s2 : s1;
        float g2 = cw;
        #pragma unroll
        for (int off = 1; off < 64; off <<= 1) g2 = fminf(g2, __shfl_xor(g2, off));
        u32 t2 = (cw == g2) ? cr : 0xFFFFFFFFu;
        #pragma unroll
        for (int off = 1; off < 64; off <<= 1){
          u32 o = (u32)__shfl_xor((int)t2, off); t2 = o < t2 ? o : t2;
        }
        u32 r2w = (u32)__builtin_amdgcn_readfirstlane((int)t2);
        // install fresh exact top-2 into owner lane's slot
        if (lane == (jj >> 1)){
          if (jj & 1){ b1 = g1; br1 = r1w; b2 = g2; br2 = r2w; }
          else       { a1 = g1; ar1 = r1w; a2 = g2; ar2 = r2w; }
        }
        continue;   // retry the global reduce
      }
      gm = gms;
      break;
    }

    int i = (int)((gm >> 7) & 0x3FFu);
    int j = (int)(gm & 0x7Fu);
    if (lane == 0){
      outsrc[b*NT + step] = (float)i;
      outtgt[b*NT + step] = (float)j;
    }

    // mark row i dead (wave-uniform, static-indexed)
    #pragma unroll
    for (int k = 0; k < KROWS; ++k)
      if ((i >> 6) == k) rd[k] |= (1ull << (i & 63));

    // E1: retire column j
    if (lane == (int)(j >> 1)){
      if (j & 1){ b1 = INFINITY; br1 = 0x7FFu; br2 |= 0x400u; }
      else      { a1 = INFINITY; ar1 = 0x7FFu; ar2 |= 0x400u; }
    }

    // E2: row i died — per-column top-2 maintenance
    {
      bool ca = (ar2 == (u32)i);          // slot2 alive & row==i (flags make !=)
      bool cb = (ar1 == (u32)i);          // slot1 exact & row==i
      a1  = cb ? a2  : a1;
      ar1 = cb ? ar2 : ar1;               // inherits DEAD -> STALE
      ar2 = (ca || cb) ? (ar2 | 0x400u) : ar2;
    }
    {
      bool ca = (br2 == (u32)i);
      bool cb = (br1 == (u32)i);
      b1  = cb ? b2  : b1;
      br1 = cb ? br2 : br1;
      br2 = (ca || cb) ? (br2 | 0x400u) : br2;
    }
  }
}

extern "C" void kernel_launch(void* const* d_in, const int* in_sizes, int n_in,
                              void* d_out, int out_size, void* d_ws, size_t ws_size,
                              hipStream_t stream){
  const float* logits = (const float*)d_in[0];
  const float* pboxes = (const float*)d_in[1];
  const int*   labels = (const int*)  d_in[2];
  const float* tboxes = (const float*)d_in[3];
  int B = in_sizes[0] / (NQ * NC);

  float* out    = (float*)d_out;
  float* outsrc = out;
  float* outtgt = out + (size_t)B * NT;
  float* Cmat   = out + (size_t)2 * B * NT;
  float* stats  = (float*)d_ws;          // B*NQ*2 floats

  int nrows = B * NQ;
  int blocks0 = (nrows + 3) / 4;
  softmax_stats_kernel<<<blocks0, 256, 0, stream>>>(logits, stats, nrows);

  int total = B * NQ * NT;
  cost_kernel<<<(total + 255) / 256, 256, 0, stream>>>(logits, pboxes, labels,
                                                       tboxes, stats, Cmat, total);

  greedy_kernel<<<B, 64, 0, stream>>>(Cmat, outsrc, outtgt);
}

// Round 7
// 274.995 us; speedup vs baseline: 16.4152x; 1.2608x over previous
//
#include <hip/hip_runtime.h>
#include <cstdint>
#include <math.h>

#define NQ 900
#define NT 128
#define NC 91
#define KROWS 15   // ceil(900/64)
#define NCH 10     // row chunks for colmin init (900/10 = 90 rows each)

typedef unsigned long long u64;
typedef unsigned int u32;

// monotone (total-order-preserving) mapping f32 -> u32
__device__ __forceinline__ u32 fmono(float f){
  u32 u = __float_as_uint(f);
  return (u & 0x80000000u) ? ~u : (u | 0x80000000u);
}

// ---------------- kernel 0: per-(b,q) softmax max & denom (UNCHANGED) ----------------
__global__ void softmax_stats_kernel(const float* __restrict__ logits,
                                     float* __restrict__ stats, int nrows){
  int gw   = (int)((blockIdx.x * blockDim.x + threadIdx.x) >> 6);
  int lane = threadIdx.x & 63;
  if (gw >= nrows) return;
  const float* row = logits + (size_t)gw * NC;
  float v0 = (lane      < NC) ? row[lane]      : -INFINITY;
  float v1 = (lane + 64 < NC) ? row[lane + 64] : -INFINITY;
  float m = fmaxf(v0, v1);
  #pragma unroll
  for (int off = 32; off; off >>= 1) m = fmaxf(m, __shfl_xor(m, off));
  float s = ((lane < NC) ? expf(v0 - m) : 0.0f)
          + ((lane + 64 < NC) ? expf(v1 - m) : 0.0f);
  #pragma unroll
  for (int off = 32; off; off >>= 1) s += __shfl_xor(s, off);
  if (lane == 0){ stats[2*gw] = m; stats[2*gw+1] = s; }
}

// ---------------- kernel 1: cost matrix C[b][q][t] (UNCHANGED — bit-exact) ----------------
__global__ void cost_kernel(const float* __restrict__ logits,
                            const float* __restrict__ pboxes,
                            const int*   __restrict__ labels,
                            const float* __restrict__ tboxes,
                            const float* __restrict__ stats,
                            float* __restrict__ Cout, int total){
#pragma clang fp contract(off)
  int idx = blockIdx.x * blockDim.x + threadIdx.x;
  if (idx >= total) return;
  int t  = idx & (NT - 1);
  int bq = idx >> 7;            // NT == 128
  int b  = bq / NQ;

  int   lab = labels[b*NT + t];
  float l   = logits[(size_t)bq*NC + lab];
  float m   = stats[2*bq], s = stats[2*bq+1];
  float cclass = -(expf(l - m) / s);

  const float* pb = pboxes + (size_t)bq*4;
  const float* tb = tboxes + ((size_t)b*NT + t)*4;
  float pcx = pb[0], pcy = pb[1], pw = pb[2], ph = pb[3];
  float tcx = tb[0], tcy = tb[1], tw = tb[2], th = tb[3];

  float cbbox = ((fabsf(pcx-tcx) + fabsf(pcy-tcy)) + fabsf(pw-tw)) + fabsf(ph-th);

  float px0 = pcx - 0.5f*pw, py0 = pcy - 0.5f*ph;
  float px1 = pcx + 0.5f*pw, py1 = pcy + 0.5f*ph;
  float tx0 = tcx - 0.5f*tw, ty0 = tcy - 0.5f*th;
  float tx1 = tcx + 0.5f*tw, ty1 = tcy + 0.5f*th;

  float area1 = (px1 - px0) * (py1 - py0);
  float area2 = (tx1 - tx0) * (ty1 - ty0);
  float ltx = fmaxf(px0, tx0), lty = fmaxf(py0, ty0);
  float rbx = fminf(px1, tx1), rby = fminf(py1, ty1);
  float wx = fmaxf(rbx - ltx, 0.0f), wy = fmaxf(rby - lty, 0.0f);
  float inter = wx * wy;
  float uni   = (area1 + area2) - inter;
  float iou   = inter / uni;
  float cx0 = fminf(px0, tx0), cy0 = fminf(py0, ty0);
  float cx1 = fmaxf(px1, tx1), cy1 = fmaxf(py1, ty1);
  float cwx = fmaxf(cx1 - cx0, 0.0f), cwy = fmaxf(cy1 - cy0, 0.0f);
  float areac = cwx * cwy;
  float giou  = iou - (areac - uni) / areac;

  float cost = (cclass + 5.0f*cbbox) - 2.0f*giou;
  Cout[idx] = cost;
}

// ---------------- kernel 1.5: per-column argmin via u64 atomicMin ----------------
// key = (fmono(val)<<32) | row  -> u64 min == (val,row) lexicographic
// == first-occurrence column argmin, independent of chunk merge order.
__global__ __launch_bounds__(128) void colmin_kernel(const float* __restrict__ Cmat,
                                                     u64* __restrict__ colmin){
  int b  = blockIdx.x / NCH;
  int ch = blockIdx.x - b * NCH;
  int t  = threadIdx.x;                      // column 0..127
  const float* Cb = Cmat + (size_t)b * NQ * NT + t;
  int r0 = ch * (NQ / NCH);
  u64 best = ~0ull;
  #pragma unroll 6
  for (int r = r0; r < r0 + NQ/NCH; ++r){
    float v = Cb[(size_t)r * NT];
    u64 k = ((u64)fmono(v) << 32) | (u32)r;
    best = k < best ? k : best;
  }
  atomicMin(&colmin[b * NT + t], best);
}

// ---------------- kernel 2: greedy matching — 1 wave/batch, register-resident ----------------
// Per-lane 2 columns, each one u64 key: kv(mono)<<20 | stale<<17 | row<<7 | col.
// u64 wave-min == reference (val, row, col) flat argmin. Stale columns carry a
// lower bound from a dead row; they lose ties to fresh keys (bit17) and are
// rescanned lazily only when they win a pop.
__global__ __launch_bounds__(64) void greedy_kernel(const float* __restrict__ Cmat,
                                                    const u64* __restrict__ colmin,
                                                    float* __restrict__ outsrc,
                                                    float* __restrict__ outtgt){
  const int b    = blockIdx.x;
  const int lane = threadIdx.x;          // 0..63
  const float* Cb = Cmat + (size_t)b * NQ * NT;
  const u32 colA = 2*lane, colB = 2*lane + 1;

  // load init column argmins (one 16B load per lane)
  ulonglong2 kk = ((const ulonglong2*)(colmin + (size_t)b * NT))[lane];
  u64 keyA, keyB;
  {
    u32 mono = (u32)(kk.x >> 32), row = (u32)kk.x & 0x3FFu;
    keyA = ((u64)mono << 20) | (row << 7) | colA;
    mono = (u32)(kk.y >> 32); row = (u32)kk.y & 0x3FFu;
    keyB = ((u64)mono << 20) | (row << 7) | colB;
  }

  // dead-row bitmask: rd[k] bit L <=> row 64k+L dead (wave-uniform content)
  u64 rd[KROWS];
  #pragma unroll
  for (int k = 0; k < KROWS; ++k) rd[k] = 0;

  for (int step = 0; step < NT; ++step){
    u64 g;
    while (true){
      u64 cand = keyA < keyB ? keyA : keyB;
      #pragma unroll
      for (int off = 1; off < 64; off <<= 1){
        u64 o = __shfl_xor(cand, off);
        cand = o < cand ? o : cand;
      }
      if (!((cand >> 17) & 1ull)){ g = cand; break; }

      // ---- lazy rescan of stale column jj over active rows (cooperative) ----
      int jj = (int)(cand & 0x7Fu);
      u64 best = ~0ull;
      #pragma unroll
      for (int k = 0; k < KROWS; ++k){
        int r = lane + 64*k;
        u64 c2 = ~0ull;
        if (r < NQ){
          float v = Cb[(size_t)r * NT + jj];
          bool dead = ((rd[k] >> lane) & 1ull) != 0ull;
          c2 = dead ? ~0ull : (((u64)fmono(v) << 32) | (u32)r);
        }
        best = c2 < best ? c2 : best;
      }
      #pragma unroll
      for (int off = 1; off < 64; off <<= 1){
        u64 o = __shfl_xor(best, off);
        best = o < best ? o : best;
      }
      if (lane == (jj >> 1)){
        u32 mono = (u32)(best >> 32), row = (u32)best & 0x3FFu;
        u64 nk = ((u64)mono << 20) | (row << 7) | (u32)jj;
        if (jj & 1) keyB = nk; else keyA = nk;
      }
    }

    int i = (int)((g >> 7) & 0x3FFu);
    int j = (int)(g & 0x7Fu);
    if (lane == 0){
      outsrc[b*NT + step] = (float)i;
      outtgt[b*NT + step] = (float)j;
    }

    // mark row i dead (static-indexed unroll)
    #pragma unroll
    for (int k = 0; k < KROWS; ++k)
      if ((i >> 6) == k) rd[k] |= (1ull << (i & 63));

    // retire column j
    if (lane == (j >> 1)){
      if (j & 1) keyB = ~0ull; else keyA = ~0ull;
    }
    // columns whose cached argmin row died -> stale (value stays as lower bound)
    if (((keyA >> 7) & 0x3FFu) == (u32)i) keyA |= (1ull << 17);
    if (((keyB >> 7) & 0x3FFu) == (u32)i) keyB |= (1ull << 17);
  }
}

extern "C" void kernel_launch(void* const* d_in, const int* in_sizes, int n_in,
                              void* d_out, int out_size, void* d_ws, size_t ws_size,
                              hipStream_t stream){
  const float* logits = (const float*)d_in[0];
  const float* pboxes = (const float*)d_in[1];
  const int*   labels = (const int*)  d_in[2];
  const float* tboxes = (const float*)d_in[3];
  int B = in_sizes[0] / (NQ * NC);

  float* out    = (float*)d_out;
  float* outsrc = out;
  float* outtgt = out + (size_t)B * NT;
  float* Cmat   = out + (size_t)2 * B * NT;

  // ws layout: stats (B*NQ*2 floats) is dead after cost_kernel;
  // colmin (B*NT u64, 64KB) aliases its head afterwards.
  float* stats  = (float*)d_ws;
  u64*   colmin = (u64*)d_ws;

  int nrows = B * NQ;
  int blocks0 = (nrows + 3) / 4;
  softmax_stats_kernel<<<blocks0, 256, 0, stream>>>(logits, stats, nrows);

  int total = B * NQ * NT;
  cost_kernel<<<(total + 255) / 256, 256, 0, stream>>>(logits, pboxes, labels,
                                                       tboxes, stats, Cmat, total);

  // stats no longer needed; reuse as colmin
  hipMemsetAsync(colmin, 0xFF, (size_t)B * NT * sizeof(u64), stream);
  colmin_kernel<<<B * NCH, 128, 0, stream>>>(Cmat, colmin);

  greedy_kernel<<<B, 64, 0, stream>>>(Cmat, colmin, outsrc, outtgt);
}

// Round 9
// 247.054 us; speedup vs baseline: 18.2717x; 1.1131x over previous
//
#include <hip/hip_runtime.h>
#include <cstdint>
#include <math.h>

#define NQ 900
#define NT 128
#define NC 91
#define KROWS 15   // ceil(900/64)
#define NCH 10     // row chunks for colmin init (900/10 = 90 rows each)

typedef unsigned long long u64;
typedef unsigned int u32;

// monotone (total-order-preserving) mapping f32 -> u32
__device__ __forceinline__ u32 fmono(float f){
  u32 u = __float_as_uint(f);
  return (u & 0x80000000u) ? ~u : (u | 0x80000000u);
}

// ---- wave64 u64 min via DPP (VALU pipe, no LDS): canonical GCN sequence ----
// row_shr:1/2/4/8 accumulate within 16-lane rows; bcast15 (mask 0xa) merges
// row0->1, row2->3; bcast31 (mask 0xc) merges rows 0,1 -> 2,3. Full min lands
// in lane 63; readlane(63) returns it wave-uniform (SGPR).
template<int CTRL, int RMASK>
__device__ __forceinline__ u64 dpp_min_stage(u64 x){
  u32 lo = (u32)x, hi = (u32)(x >> 32);
  u32 lo2 = (u32)__builtin_amdgcn_update_dpp((int)lo, (int)lo, CTRL, RMASK, 0xf, false);
  u32 hi2 = (u32)__builtin_amdgcn_update_dpp((int)hi, (int)hi, CTRL, RMASK, 0xf, false);
  u64 y = ((u64)hi2 << 32) | lo2;
  return y < x ? y : x;
}
__device__ __forceinline__ u64 wave_min_u64(u64 x){
  x = dpp_min_stage<0x111, 0xf>(x);   // row_shr:1
  x = dpp_min_stage<0x112, 0xf>(x);   // row_shr:2
  x = dpp_min_stage<0x114, 0xf>(x);   // row_shr:4
  x = dpp_min_stage<0x118, 0xf>(x);   // row_shr:8
  x = dpp_min_stage<0x142, 0xa>(x);   // row_bcast:15 -> rows 1,3
  x = dpp_min_stage<0x143, 0xc>(x);   // row_bcast:31 -> rows 2,3
  u32 lo = (u32)__builtin_amdgcn_readlane((int)(u32)x, 63);
  u32 hi = (u32)__builtin_amdgcn_readlane((int)(u32)(x >> 32), 63);
  return ((u64)hi << 32) | lo;
}

// ---------------- kernel 0: per-(b,q) softmax max & denom (UNCHANGED) ----------------
__global__ void softmax_stats_kernel(const float* __restrict__ logits,
                                     float* __restrict__ stats, int nrows){
  int gw   = (int)((blockIdx.x * blockDim.x + threadIdx.x) >> 6);
  int lane = threadIdx.x & 63;
  if (gw >= nrows) return;
  const float* row = logits + (size_t)gw * NC;
  float v0 = (lane      < NC) ? row[lane]      : -INFINITY;
  float v1 = (lane + 64 < NC) ? row[lane + 64] : -INFINITY;
  float m = fmaxf(v0, v1);
  #pragma unroll
  for (int off = 32; off; off >>= 1) m = fmaxf(m, __shfl_xor(m, off));
  float s = ((lane < NC) ? expf(v0 - m) : 0.0f)
          + ((lane + 64 < NC) ? expf(v1 - m) : 0.0f);
  #pragma unroll
  for (int off = 32; off; off >>= 1) s += __shfl_xor(s, off);
  if (lane == 0){ stats[2*gw] = m; stats[2*gw+1] = s; }
}

// ---------------- kernel 1: cost matrix C[b][q][t] (UNCHANGED — bit-exact) ----------------
__global__ void cost_kernel(const float* __restrict__ logits,
                            const float* __restrict__ pboxes,
                            const int*   __restrict__ labels,
                            const float* __restrict__ tboxes,
                            const float* __restrict__ stats,
                            float* __restrict__ Cout, int total){
#pragma clang fp contract(off)
  int idx = blockIdx.x * blockDim.x + threadIdx.x;
  if (idx >= total) return;
  int t  = idx & (NT - 1);
  int bq = idx >> 7;            // NT == 128
  int b  = bq / NQ;

  int   lab = labels[b*NT + t];
  float l   = logits[(size_t)bq*NC + lab];
  float m   = stats[2*bq], s = stats[2*bq+1];
  float cclass = -(expf(l - m) / s);

  const float* pb = pboxes + (size_t)bq*4;
  const float* tb = tboxes + ((size_t)b*NT + t)*4;
  float pcx = pb[0], pcy = pb[1], pw = pb[2], ph = pb[3];
  float tcx = tb[0], tcy = tb[1], tw = tb[2], th = tb[3];

  float cbbox = ((fabsf(pcx-tcx) + fabsf(pcy-tcy)) + fabsf(pw-tw)) + fabsf(ph-th);

  float px0 = pcx - 0.5f*pw, py0 = pcy - 0.5f*ph;
  float px1 = pcx + 0.5f*pw, py1 = pcy + 0.5f*ph;
  float tx0 = tcx - 0.5f*tw, ty0 = tcy - 0.5f*th;
  float tx1 = tcx + 0.5f*tw, ty1 = tcy + 0.5f*th;

  float area1 = (px1 - px0) * (py1 - py0);
  float area2 = (tx1 - tx0) * (ty1 - ty0);
  float ltx = fmaxf(px0, tx0), lty = fmaxf(py0, ty0);
  float rbx = fminf(px1, tx1), rby = fminf(py1, ty1);
  float wx = fmaxf(rbx - ltx, 0.0f), wy = fmaxf(rby - lty, 0.0f);
  float inter = wx * wy;
  float uni   = (area1 + area2) - inter;
  float iou   = inter / uni;
  float cx0 = fminf(px0, tx0), cy0 = fminf(py0, ty0);
  float cx1 = fmaxf(px1, tx1), cy1 = fmaxf(py1, ty1);
  float cwx = fmaxf(cx1 - cx0, 0.0f), cwy = fmaxf(cy1 - cy0, 0.0f);
  float areac = cwx * cwy;
  float giou  = iou - (areac - uni) / areac;

  float cost = (cclass + 5.0f*cbbox) - 2.0f*giou;
  Cout[idx] = cost;
}

// ---------------- kernel 1.5: per-column argmin via u64 atomicMin (UNCHANGED) ----------------
__global__ __launch_bounds__(128) void colmin_kernel(const float* __restrict__ Cmat,
                                                     u64* __restrict__ colmin){
  int b  = blockIdx.x / NCH;
  int ch = blockIdx.x - b * NCH;
  int t  = threadIdx.x;                      // column 0..127
  const float* Cb = Cmat + (size_t)b * NQ * NT + t;
  int r0 = ch * (NQ / NCH);
  u64 best = ~0ull;
  #pragma unroll 6
  for (int r = r0; r < r0 + NQ/NCH; ++r){
    float v = Cb[(size_t)r * NT];
    u64 k = ((u64)fmono(v) << 32) | (u32)r;
    best = k < best ? k : best;
  }
  atomicMin(&colmin[b * NT + t], best);
}

// ---------------- kernel 2: greedy matching — 1 wave/batch, DPP reduce ----------------
// Per-lane 2 columns, each one u64 key: kv(mono)<<20 | stale<<17 | row<<7 | col.
// wave-min(u64) == reference (val, row, col) flat argmin. Stale columns carry a
// lower bound from a dead row; rescanned lazily only when they win a pop.
__global__ __launch_bounds__(64) void greedy_kernel(const float* __restrict__ Cmat,
                                                    const u64* __restrict__ colmin,
                                                    float* __restrict__ outsrc,
                                                    float* __restrict__ outtgt){
  const int b    = blockIdx.x;
  const int lane = threadIdx.x;          // 0..63
  const float* Cb = Cmat + (size_t)b * NQ * NT;
  const u32 colA = 2*lane, colB = 2*lane + 1;

  // load init column argmins (one 16B load per lane)
  ulonglong2 kk = ((const ulonglong2*)(colmin + (size_t)b * NT))[lane];
  u64 keyA, keyB;
  {
    u32 mono = (u32)(kk.x >> 32), row = (u32)kk.x & 0x3FFu;
    keyA = ((u64)mono << 20) | (row << 7) | colA;
    mono = (u32)(kk.y >> 32); row = (u32)kk.y & 0x3FFu;
    keyB = ((u64)mono << 20) | (row << 7) | colB;
  }

  // dead-row bitmask: rd[k] bit L <=> row 64k+L dead
  u64 rd[KROWS];
  #pragma unroll
  for (int k = 0; k < KROWS; ++k) rd[k] = 0;

  for (int step = 0; step < NT; ++step){
    u64 g;
    while (true){
      u64 cand = wave_min_u64(keyA < keyB ? keyA : keyB);   // wave-uniform
      if (!((cand >> 17) & 1ull)){ g = cand; break; }

      // ---- lazy rescan of stale column jj over active rows (cooperative) ----
      int jj = (int)(cand & 0x7Fu);
      u64 best = ~0ull;
      #pragma unroll
      for (int k = 0; k < KROWS; ++k){
        int r = lane + 64*k;
        u64 c2 = ~0ull;
        if (r < NQ){
          float v = Cb[(size_t)r * NT + jj];
          bool dead = ((rd[k] >> lane) & 1ull) != 0ull;
          c2 = dead ? ~0ull : (((u64)fmono(v) << 32) | (u32)r);
        }
        best = c2 < best ? c2 : best;
      }
      best = wave_min_u64(best);                            // wave-uniform
      if (lane == (jj >> 1)){
        u32 mono = (u32)(best >> 32), row = (u32)best & 0x3FFu;
        u64 nk = ((u64)mono << 20) | (row << 7) | (u32)jj;
        if (jj & 1) keyB = nk; else keyA = nk;
      }
    }

    int i = (int)((g >> 7) & 0x3FFu);
    int j = (int)(g & 0x7Fu);
    if (lane == 0){
      outsrc[b*NT + step] = (float)i;
      outtgt[b*NT + step] = (float)j;
    }

    // mark row i dead (static-indexed unroll)
    #pragma unroll
    for (int k = 0; k < KROWS; ++k)
      if ((i >> 6) == k) rd[k] |= (1ull << (i & 63));

    // retire column j
    if (lane == (j >> 1)){
      if (j & 1) keyB = ~0ull; else keyA = ~0ull;
    }
    // columns whose cached argmin row died -> stale (value stays as lower bound)
    if (((keyA >> 7) & 0x3FFu) == (u32)i) keyA |= (1ull << 17);
    if (((keyB >> 7) & 0x3FFu) == (u32)i) keyB |= (1ull << 17);
  }
}

extern "C" void kernel_launch(void* const* d_in, const int* in_sizes, int n_in,
                              void* d_out, int out_size, void* d_ws, size_t ws_size,
                              hipStream_t stream){
  const float* logits = (const float*)d_in[0];
  const float* pboxes = (const float*)d_in[1];
  const int*   labels = (const int*)  d_in[2];
  const float* tboxes = (const float*)d_in[3];
  int B = in_sizes[0] / (NQ * NC);

  float* out    = (float*)d_out;
  float* outsrc = out;
  float* outtgt = out + (size_t)B * NT;
  float* Cmat   = out + (size_t)2 * B * NT;

  // ws layout: stats (B*NQ*2 floats) is dead after cost_kernel;
  // colmin (B*NT u64, 64KB) aliases its head afterwards.
  float* stats  = (float*)d_ws;
  u64*   colmin = (u64*)d_ws;

  int nrows = B * NQ;
  int blocks0 = (nrows + 3) / 4;
  softmax_stats_kernel<<<blocks0, 256, 0, stream>>>(logits, stats, nrows);

  int total = B * NQ * NT;
  cost_kernel<<<(total + 255) / 256, 256, 0, stream>>>(logits, pboxes, labels,
                                                       tboxes, stats, Cmat, total);

  // stats no longer needed; reuse as colmin
  hipMemsetAsync(colmin, 0xFF, (size_t)B * NT * sizeof(u64), stream);
  colmin_kernel<<<B * NCH, 128, 0, stream>>>(Cmat, colmin);

  greedy_kernel<<<B, 64, 0, stream>>>(Cmat, colmin, outsrc, outtgt);
}

// Round 10
// 245.971 us; speedup vs baseline: 18.3522x; 1.0044x over previous
//
#include <hip/hip_runtime.h>
#include <cstdint>
#include <math.h>

#define NQ 900
#define NT 128
#define NC 91
#define KROWS 15   // ceil(900/64)
#define NCH 10     // row chunks for colmin partials (900/10 = 90 rows each)

typedef unsigned long long u64;
typedef unsigned int u32;

// monotone (total-order-preserving) mapping f32 -> u32 (colmin partial keys)
__device__ __forceinline__ u32 fmono(float f){
  u32 u = __float_as_uint(f);
  return (u & 0x80000000u) ? ~u : (u | 0x80000000u);
}
__device__ __forceinline__ float fmono_inv(u32 m){
  u32 u = (m & 0x80000000u) ? (m & 0x7FFFFFFFu) : ~m;
  return __uint_as_float(u);
}

// ---- wave64 argmin via DPP f32 min + ballot tie-resolve ----
// DPP ctrl sequence (row_shr 1/2/4/8, bcast15 mask 0xa, bcast31 mask 0xc)
// proven on this HW in R8/R9 (u64 payload, absmax 0.0). Result in lane 63.
// Returns winning meta (uniform); *gout = min value (uniform).
// Tie rule: among lanes with lv==gv, smallest meta wins == (val,row,col)
// flat-argmin order; stale bit 24 makes bounds lose ties to fresh keys.
__device__ __forceinline__ u32 wave_argmin(float lv, u32 lm, float* gout){
  float x = lv;
  #define FSTG(C,RM) { int t_ = __builtin_amdgcn_update_dpp(__float_as_int(x), __float_as_int(x), C, RM, 0xf, false); x = fminf(x, __int_as_float(t_)); }
  FSTG(0x111,0xf) FSTG(0x112,0xf) FSTG(0x114,0xf) FSTG(0x118,0xf)
  FSTG(0x142,0xa) FSTG(0x143,0xc)
  #undef FSTG
  float gv = __int_as_float(__builtin_amdgcn_readlane(__float_as_int(x), 63));
  *gout = gv;
  u64 tie = __ballot(lv == gv);
  if (__popcll(tie) == 1){
    int w = (int)__ffsll((long long)tie) - 1;
    return (u32)__builtin_amdgcn_readlane((int)lm, w);
  }
  u32 m = (lv == gv) ? lm : 0xFFFFFFFFu;
  #define USTG(C,RM) { u32 t_ = (u32)__builtin_amdgcn_update_dpp((int)m, (int)m, C, RM, 0xf, false); m = t_ < m ? t_ : m; }
  USTG(0x111,0xf) USTG(0x112,0xf) USTG(0x114,0xf) USTG(0x118,0xf)
  USTG(0x142,0xa) USTG(0x143,0xc)
  #undef USTG
  return (u32)__builtin_amdgcn_readlane((int)m, 63);
}

// ---------------- kernel 1: fused softmax-stats + cost matrix ----------------
// Block = 256 threads covering rows {2*blk, 2*blk+1} x 128 cols.
// Waves 0/2 compute each row's softmax (m,s) with the EXACT op order of the
// previous standalone kernel (validated bit-exact), publish via LDS.
__global__ __launch_bounds__(256) void cost_kernel(const float* __restrict__ logits,
                                                   const float* __restrict__ pboxes,
                                                   const int*   __restrict__ labels,
                                                   const float* __restrict__ tboxes,
                                                   float* __restrict__ Cout){
#pragma clang fp contract(off)
  int blk = blockIdx.x, tid = threadIdx.x;
  int idx = blk * 256 + tid;
  int t   = idx & (NT - 1);
  int bq  = idx >> 7;            // NT == 128
  int b   = bq / NQ;
  int wid = tid >> 6, lane = tid & 63;

  __shared__ float sm_m[2], sm_s[2];
  if ((wid & 1) == 0){           // waves 0 and 2 -> rows blk*2, blk*2+1
    int r = blk * 2 + (wid >> 1);
    const float* row = logits + (size_t)r * NC;
    float v0 = (lane      < NC) ? row[lane]      : -INFINITY;
    float v1 = (lane + 64 < NC) ? row[lane + 64] : -INFINITY;
    float m = fmaxf(v0, v1);
    #pragma unroll
    for (int off = 32; off; off >>= 1) m = fmaxf(m, __shfl_xor(m, off));
    float s = ((lane < NC) ? expf(v0 - m) : 0.0f)
            + ((lane + 64 < NC) ? expf(v1 - m) : 0.0f);
    #pragma unroll
    for (int off = 32; off; off >>= 1) s += __shfl_xor(s, off);
    if (lane == 0){ sm_m[wid >> 1] = m; sm_s[wid >> 1] = s; }
  }
  __syncthreads();
  float m = sm_m[tid >> 7], s = sm_s[tid >> 7];

  int   lab = labels[b*NT + t];
  float l   = logits[(size_t)bq*NC + lab];
  float cclass = -(expf(l - m) / s);

  const float* pb = pboxes + (size_t)bq*4;
  const float* tb = tboxes + ((size_t)b*NT + t)*4;
  float pcx = pb[0], pcy = pb[1], pw = pb[2], ph = pb[3];
  float tcx = tb[0], tcy = tb[1], tw = tb[2], th = tb[3];

  float cbbox = ((fabsf(pcx-tcx) + fabsf(pcy-tcy)) + fabsf(pw-tw)) + fabsf(ph-th);

  float px0 = pcx - 0.5f*pw, py0 = pcy - 0.5f*ph;
  float px1 = pcx + 0.5f*pw, py1 = pcy + 0.5f*ph;
  float tx0 = tcx - 0.5f*tw, ty0 = tcy - 0.5f*th;
  float tx1 = tcx + 0.5f*tw, ty1 = tcy + 0.5f*th;

  float area1 = (px1 - px0) * (py1 - py0);
  float area2 = (tx1 - tx0) * (ty1 - ty0);
  float ltx = fmaxf(px0, tx0), lty = fmaxf(py0, ty0);
  float rbx = fminf(px1, tx1), rby = fminf(py1, ty1);
  float wx = fmaxf(rbx - ltx, 0.0f), wy = fmaxf(rby - lty, 0.0f);
  float inter = wx * wy;
  float uni   = (area1 + area2) - inter;
  float iou   = inter / uni;
  float cx0 = fminf(px0, tx0), cy0 = fminf(py0, ty0);
  float cx1 = fmaxf(px1, tx1), cy1 = fmaxf(py1, ty1);
  float cwx = fmaxf(cx1 - cx0, 0.0f), cwy = fmaxf(cy1 - cy0, 0.0f);
  float areac = cwx * cwy;
  float giou  = iou - (areac - uni) / areac;

  float cost = (cclass + 5.0f*cbbox) - 2.0f*giou;
  Cout[idx] = cost;
}

// ---------------- kernel 1.5: per-column chunk-partial argmin (no atomics) ----------------
// part[b][ch][t] = min over rows of chunk ch of ((fmono(val)<<32)|row)
__global__ __launch_bounds__(128) void colmin_kernel(const float* __restrict__ Cmat,
                                                     u64* __restrict__ part){
  int b  = blockIdx.x / NCH;
  int ch = blockIdx.x - b * NCH;
  int t  = threadIdx.x;                      // column 0..127
  const float* Cb = Cmat + (size_t)b * NQ * NT + t;
  int r0 = ch * (NQ / NCH);
  u64 best = ~0ull;
  #pragma unroll 6
  for (int r = r0; r < r0 + NQ/NCH; ++r){
    float v = Cb[(size_t)r * NT];
    u64 k = ((u64)fmono(v) << 32) | (u32)r;
    best = k < best ? k : best;
  }
  part[((size_t)b * NCH + ch) * NT + t] = best;
}

// ---------------- kernel 2: greedy matching — 1 wave/batch, f32-DPP + ballot pops ----------------
// Per-lane 2 columns, each (float val, u32 meta); meta = stale<<24 | row<<7 | col.
// Stale columns carry a lower bound from a dead row; rescanned lazily on pop-win.
__global__ __launch_bounds__(64) void greedy_kernel(const float* __restrict__ Cmat,
                                                    const u64* __restrict__ part,
                                                    float* __restrict__ outsrc,
                                                    float* __restrict__ outtgt){
  const int b    = blockIdx.x;
  const int lane = threadIdx.x;          // 0..63
  const float* Cb = Cmat + (size_t)b * NQ * NT;
  const u32 colA = 2*lane, colB = 2*lane + 1;

  // init: merge the 10 chunk partials per column (u64 min is order-independent)
  u64 kA = ~0ull, kB = ~0ull;
  #pragma unroll
  for (int ch = 0; ch < NCH; ++ch){
    ulonglong2 p = ((const ulonglong2*)(part + ((size_t)b * NCH + ch) * NT))[lane];
    kA = p.x < kA ? p.x : kA;
    kB = p.y < kB ? p.y : kB;
  }
  float vA = fmono_inv((u32)(kA >> 32));
  float vB = fmono_inv((u32)(kB >> 32));
  u32 mA = ((((u32)kA) & 0x3FFu) << 7) | colA;
  u32 mB = ((((u32)kB) & 0x3FFu) << 7) | colB;

  // dead-row bitmask: rd[k] bit L <=> row 64k+L dead
  u64 rd[KROWS];
  #pragma unroll
  for (int k = 0; k < KROWS; ++k) rd[k] = 0;

  for (int step = 0; step < NT; ++step){
    u32 gm;
    while (true){
      bool bsel = (vB < vA) || ((vB == vA) && (mB < mA));
      float lv = bsel ? vB : vA;
      u32   lm = bsel ? mB : mA;
      float gv;
      u32 g = wave_argmin(lv, lm, &gv);
      if (!(g >> 24)){ gm = g; break; }

      // ---- lazy rescan of stale column jj over active rows (cooperative) ----
      int jj = (int)(g & 0x7Fu);
      float w1 = INFINITY; u32 s1 = 0;
      #pragma unroll
      for (int k = 0; k < KROWS; ++k){
        int r = lane + 64*k;
        if (r < NQ){
          float v = Cb[(size_t)r * NT + jj];
          bool dead = ((rd[k] >> lane) & 1ull) != 0ull;
          v = dead ? INFINITY : v;
          if (v < w1){ w1 = v; s1 = (u32)r; }   // ascending r -> first occurrence
        }
      }
      float rgv;
      u32 rrow = wave_argmin(w1, s1, &rgv);
      if (lane == (jj >> 1)){
        if (jj & 1){ vB = rgv; mB = (rrow << 7) | (u32)jj; }
        else       { vA = rgv; mA = (rrow << 7) | (u32)jj; }
      }
    }

    int i = (int)((gm >> 7) & 0x3FFu);
    int j = (int)(gm & 0x7Fu);
    if (lane == 0){
      outsrc[b*NT + step] = (float)i;
      outtgt[b*NT + step] = (float)j;
    }

    // mark row i dead (static-indexed unroll)
    #pragma unroll
    for (int k = 0; k < KROWS; ++k)
      if ((i >> 6) == k) rd[k] |= (1ull << (i & 63));

    // retire column j (row field 0x3FF can never equal i <= 899)
    if (lane == (j >> 1)){
      if (j & 1){ vB = INFINITY; mB = 0x00FFFFFFu & ~(1u<<24); mB = 0x00FFFFFFu; }
      else      { vA = INFINITY; mA = 0x00FFFFFFu; }
    }
    // columns whose cached argmin row died -> stale (value stays a lower bound)
    if (((mA >> 7) & 0x3FFu) == (u32)i) mA |= (1u << 24);
    if (((mB >> 7) & 0x3FFu) == (u32)i) mB |= (1u << 24);
  }
}

extern "C" void kernel_launch(void* const* d_in, const int* in_sizes, int n_in,
                              void* d_out, int out_size, void* d_ws, size_t ws_size,
                              hipStream_t stream){
  const float* logits = (const float*)d_in[0];
  const float* pboxes = (const float*)d_in[1];
  const int*   labels = (const int*)  d_in[2];
  const float* tboxes = (const float*)d_in[3];
  int B = in_sizes[0] / (NQ * NC);

  float* out    = (float*)d_out;
  float* outsrc = out;
  float* outtgt = out + (size_t)B * NT;
  float* Cmat   = out + (size_t)2 * B * NT;

  u64* part = (u64*)d_ws;    // B*NCH*NT u64 = 640KB chunk partials

  int nblk = (B * NQ) / 2;   // 256 threads cover 2 rows x 128 cols
  cost_kernel<<<nblk, 256, 0, stream>>>(logits, pboxes, labels, tboxes, Cmat);

  colmin_kernel<<<B * NCH, 128, 0, stream>>>(Cmat, part);

  greedy_kernel<<<B, 64, 0, stream>>>(Cmat, part, outsrc, outtgt);
}